// Round 16
// baseline (2980.365 us; speedup 1.0000x reference)
//
#include <hip/hip_runtime.h>
#include <math.h>

#define BB 16
#define CC 128
#define LL 16000
#define KK 256
#define SS 3937
#define MM 4000
#define THRS 0.5f
#define STEP 0.1f   // float32(0.01/0.1) == 0.1f

// ---------------------------------------------------------------------------
// Strided conv1d (K=256, stride=4), fp32 register-tiled implicit GEMM.
// R14 VERBATIM (proven ~60us). Single fmaf chain per output, k ascending.
// [bit-path frozen] tx=s (coalesced epilogue), ty=c, W natural rows in LDS
// stride 68, double-buffered. x window in LDS (R15 direct-global regressed).
// MODE 0: init. MODE 1: LCA update. MODE 2: final -> hardshrink to d_out.
// ---------------------------------------------------------------------------
template<int MODE>
__global__ __launch_bounds__(256, 2) void k_conv(
    const float* __restrict__ in0,     // x (MODE 0) or recon (MODE 1/2)
    const float* __restrict__ W,       // [C][K] natural
    float* __restrict__ drive,
    float* __restrict__ u)
{
    __shared__ __align__(16) float sW[2][128 * 68];  // 2 x 34.8 KB
    __shared__ __align__(16) float sX[768];
    __shared__ int sFlag;

    const int tid = threadIdx.x;
    const int tx = tid & 15;          // s-minor
    const int ty = tid >> 4;          // c-minor
    const int s0 = blockIdx.x * 128;
    const int b  = blockIdx.y;

    const int sc = tid >> 1;
    const int sg = (tid & 1) * 8;
    const float4* W4 = (const float4*)W;

    if (tid == 0) sFlag = 0;
    __syncthreads();

    bool nz = false;
    #pragma unroll
    for (int h = 0; h < 3; ++h) {
        int t = tid + 256 * h;
        int l = 4 * s0 + t;
        float v = (l < LL) ? in0[b * LL + l] : 0.f;
        sX[t] = v;
        nz |= (v != 0.f);
    }
    if (MODE != 0) { if (nz) atomicOr(&sFlag, 1); }
    __syncthreads();

    float acc[8][8];
    #pragma unroll
    for (int i = 0; i < 8; ++i)
        #pragma unroll
        for (int j = 0; j < 8; ++j) acc[i][j] = 0.f;

    const bool doit = (MODE == 0) || (sFlag != 0);   // block-uniform

    if (doit) {
        {
            float4* dst = (float4*)sW[0];
            #pragma unroll
            for (int w = 0; w < 8; ++w)
                dst[sc * 17 + sg + w] = W4[sc * 64 + sg + w];
        }
        __syncthreads();

        for (int kc = 0; kc < 4; ++kc) {         // k chunks ascending
            float4 pre[8];
            if (kc < 3) {
                #pragma unroll
                for (int w = 0; w < 8; ++w)
                    pre[w] = W4[sc * 64 + (kc + 1) * 16 + sg + w];
            }

            const float* wbuf = sW[kc & 1];
            const int xoff = 64 * kc;

            for (int kk4 = 0; kk4 < 16; ++kk4) {          // k ascending
                float4 xq[8];
                #pragma unroll
                for (int j = 0; j < 8; ++j)
                    xq[j] = *(const float4*)&sX[4 * (tx + 16 * j) + xoff + 4 * kk4];
                float4 w4[8];
                #pragma unroll
                for (int i = 0; i < 8; ++i)
                    w4[i] = *(const float4*)&wbuf[(ty + 16 * i) * 68 + 4 * kk4];
                #pragma unroll
                for (int dk = 0; dk < 4; ++dk) {
                    #pragma unroll
                    for (int i = 0; i < 8; ++i) {
                        float wv = (&w4[i].x)[dk];
                        #pragma unroll
                        for (int j = 0; j < 8; ++j)
                            acc[i][j] = fmaf(wv, (&xq[j].x)[dk], acc[i][j]);
                    }
                }
            }

            if (kc < 3) {
                float4* dst = (float4*)sW[(kc + 1) & 1];
                #pragma unroll
                for (int w = 0; w < 8; ++w)
                    dst[sc * 17 + sg + w] = pre[w];
            }
            __syncthreads();
        }
    }

    // epilogue: locked fp32 elementwise chain; s-contiguous stores
    #pragma unroll
    for (int j = 0; j < 8; ++j) {
        int s = s0 + tx + 16 * j;
        if (s < SS) {
            #pragma unroll
            for (int i = 0; i < 8; ++i) {
                int c = ty + 16 * i;
                size_t idx = (size_t)(b * CC + c) * SS + s;
                if (MODE == 0) {
                    float d = acc[i][j];
                    drive[idx] = d;
                    u[idx] = __fmul_rn(STEP, d);   // u1 = 0 + 0.1f*drive
                } else {
                    float uo = u[idx];
                    float dr = drive[idx];
                    float a  = (fabsf(uo) > THRS) ? uo : 0.f;
                    float t1 = __fsub_rn(dr, uo);
                    float t2 = __fsub_rn(t1, acc[i][j]);
                    float t3 = __fadd_rn(t2, a);
                    float t4 = __fmul_rn(STEP, t3);
                    float un = __fadd_rn(uo, t4);
                    if (MODE == 1) u[idx] = un;
                    else           u[idx] = (fabsf(un) > THRS) ? un : 0.f;  // final
                }
            }
        }
    }
}

// ---------------------------------------------------------------------------
// float readlane via int builtin (lane is compile-time constant here)
// ---------------------------------------------------------------------------
__device__ __forceinline__ float rdlane_f(float v, int lane) {
    union { float f; int i; } u;
    u.f = v;
    u.i = __builtin_amdgcn_readlane(u.i, lane);
    return u.f;
}

// ---------------------------------------------------------------------------
// Transpose-conv (recon). Chain [bit-path frozen] identical to R5-R15:
//   recon[b][4m+r]: for c = 0..127 asc (4 stages x 32), q = 0..63 asc:
//       acc_r = fmaf(a[b][c][m-63+q], W[c][4*(63-q)+r], acc_r)
// R16 schedule: m-tile 128, 128 thr/block, grid (32,16) = 512 blocks
// -> TWO independent blocks per CU (sA 24.5 KB): one block's staging and
// barriers overlap the other's q-loop (R14's 1-block/CU config idled the
// whole CU at each barrier — the measured ~100us stall). Explicit av[8]
// batches keep >=8 ds_reads in flight. w-path: R9's coalesced b128 +
// readlane broadcast (proven).
// ---------------------------------------------------------------------------
__global__ __launch_bounds__(128, 2) void k_recon(
    const float* __restrict__ u,
    const float* __restrict__ W,       // [C][K] natural layout
    float* __restrict__ recon)         // [B][LL]
{
    __shared__ __align__(16) float sA[32 * 192];   // 24.576 KB (stride 192)
    __shared__ int sFlag;

    const int tid = threadIdx.x;      // = m_local in [0,128)
    const int lane = tid & 63;
    const int m0 = blockIdx.x * 128;
    const int b  = blockIdx.y;
    const int m  = m0 + tid;

    if (tid == 0) sFlag = 0;
    __syncthreads();

    float acc0 = 0.f, acc1 = 0.f, acc2 = 0.f, acc3 = 0.f;

    for (int cs = 0; cs < 4; ++cs) {            // 32-channel stages, c ascending
        const int c0 = cs * 32;
        // stage a = hardshrink(u): rows cl in [0,32), cols [0,191) -> m' = m0-63+col
        bool nz = false;
        for (int cl = 0; cl < 32; ++cl) {
            const float* urow = u + (size_t)(b * CC + c0 + cl) * SS + (m0 - 63);
            #pragma unroll
            for (int h = 0; h < 2; ++h) {
                int col = tid + 128 * h;
                if (col < 191) {
                    int mm = m0 - 63 + col;
                    float v = 0.f;
                    if (mm >= 0 && mm < SS) {
                        float uu = urow[col];
                        v = (fabsf(uu) > THRS) ? uu : 0.f;
                    }
                    sA[cl * 192 + col] = v;
                    nz |= (v != 0.f);
                }
            }
        }
        if (nz) atomicOr(&sFlag, 1);
        __syncthreads();                        // staging + flags complete
        const int f = sFlag;                    // block-uniform read
        __syncthreads();                        // all threads have read f
        if (tid == 0) sFlag = 0;                // reset (ordered by loop-end barrier)

        if (f) {
            for (int cl = 0; cl < 32; ++cl) {   // c ascending
                const float* arow = sA + cl * 192 + tid;     // arow[q] = a[c][m-63+q]
                float4 wv = ((const float4*)(W + (size_t)(c0 + cl) * KK))[lane];
                #pragma unroll
                for (int g = 0; g < 8; ++g) {   // q = 8g..8g+7
                    float av[8];
                    #pragma unroll
                    for (int t = 0; t < 8; ++t) av[t] = arow[8 * g + t];
                    #pragma unroll
                    for (int t = 0; t < 8; ++t) {   // q = 8g+t, j = 63-q desc
                        const int q = 8 * g + t;
                        float v  = av[t];
                        float wx = rdlane_f(wv.x, 63 - q);
                        float wy = rdlane_f(wv.y, 63 - q);
                        float wz = rdlane_f(wv.z, 63 - q);
                        float ww = rdlane_f(wv.w, 63 - q);
                        acc0 = fmaf(v, wx, acc0);
                        acc1 = fmaf(v, wy, acc1);
                        acc2 = fmaf(v, wz, acc2);
                        acc3 = fmaf(v, ww, acc3);
                    }
                }
            }
        }
        __syncthreads();   // sA reads done + sFlag reset visible before next stage
    }

    if (m < MM) {
        float4* o = (float4*)(recon + (size_t)b * LL + 4 * m);
        *o = make_float4(acc0, acc1, acc2, acc3);
    }
}

extern "C" void kernel_launch(void* const* d_in, const int* in_sizes, int n_in,
                              void* d_out, int out_size, void* d_ws, size_t ws_size,
                              hipStream_t stream) {
    const float* x = (const float*)d_in[0];   // [16][1][16000]
    const float* W = (const float*)d_in[1];   // [128][1][256]
    float* u = (float*)d_out;                 // u lives in d_out (fp32)

    float* ws    = (float*)d_ws;              // ~33.3 MB used
    float* drive = ws;                                    // 8062976
    float* recon = drive + (size_t)BB * CC * SS;          // 256000

    dim3 gConv(31, 16);   // ceil(3937/128) x B
    k_conv<0><<<gConv, 256, 0, stream>>>(x, W, drive, u);   // drive + u1

    for (int it = 0; it < 9; ++it) {   // iterations 2..10
        k_recon<<<dim3(32, 16), 128, 0, stream>>>(u, W, recon);  // 512 blocks, 2/CU
        if (it < 8)
            k_conv<1><<<gConv, 256, 0, stream>>>(recon, W, drive, u);
        else
            k_conv<2><<<gConv, 256, 0, stream>>>(recon, W, drive, u);  // final -> d_out
    }
}

// Round 17
// 2408.239 us; speedup vs baseline: 1.2376x; 1.2376x over previous
//
#include <hip/hip_runtime.h>
#include <math.h>

#define BB 16
#define CC 128
#define LL 16000
#define KK 256
#define SS 3937
#define MM 4000
#define THRS 0.5f
#define STEP 0.1f   // float32(0.01/0.1) == 0.1f

// ---------------------------------------------------------------------------
// Strided conv1d (K=256, stride=4), fp32 register-tiled implicit GEMM.
// R14 VERBATIM (proven ~60us). Single fmaf chain per output, k ascending.
// [bit-path frozen] tx=s (coalesced epilogue), ty=c, W natural rows in LDS
// stride 68, double-buffered. x window in LDS.
// MODE 0: init. MODE 1: LCA update. MODE 2: final -> hardshrink to d_out.
// ---------------------------------------------------------------------------
template<int MODE>
__global__ __launch_bounds__(256, 2) void k_conv(
    const float* __restrict__ in0,     // x (MODE 0) or recon (MODE 1/2)
    const float* __restrict__ W,       // [C][K] natural
    float* __restrict__ drive,
    float* __restrict__ u)
{
    __shared__ __align__(16) float sW[2][128 * 68];  // 2 x 34.8 KB
    __shared__ __align__(16) float sX[768];
    __shared__ int sFlag;

    const int tid = threadIdx.x;
    const int tx = tid & 15;          // s-minor
    const int ty = tid >> 4;          // c-minor
    const int s0 = blockIdx.x * 128;
    const int b  = blockIdx.y;

    const int sc = tid >> 1;
    const int sg = (tid & 1) * 8;
    const float4* W4 = (const float4*)W;

    if (tid == 0) sFlag = 0;
    __syncthreads();

    bool nz = false;
    #pragma unroll
    for (int h = 0; h < 3; ++h) {
        int t = tid + 256 * h;
        int l = 4 * s0 + t;
        float v = (l < LL) ? in0[b * LL + l] : 0.f;
        sX[t] = v;
        nz |= (v != 0.f);
    }
    if (MODE != 0) { if (nz) atomicOr(&sFlag, 1); }
    __syncthreads();

    float acc[8][8];
    #pragma unroll
    for (int i = 0; i < 8; ++i)
        #pragma unroll
        for (int j = 0; j < 8; ++j) acc[i][j] = 0.f;

    const bool doit = (MODE == 0) || (sFlag != 0);   // block-uniform

    if (doit) {
        {
            float4* dst = (float4*)sW[0];
            #pragma unroll
            for (int w = 0; w < 8; ++w)
                dst[sc * 17 + sg + w] = W4[sc * 64 + sg + w];
        }
        __syncthreads();

        for (int kc = 0; kc < 4; ++kc) {         // k chunks ascending
            float4 pre[8];
            if (kc < 3) {
                #pragma unroll
                for (int w = 0; w < 8; ++w)
                    pre[w] = W4[sc * 64 + (kc + 1) * 16 + sg + w];
            }

            const float* wbuf = sW[kc & 1];
            const int xoff = 64 * kc;

            for (int kk4 = 0; kk4 < 16; ++kk4) {          // k ascending
                float4 xq[8];
                #pragma unroll
                for (int j = 0; j < 8; ++j)
                    xq[j] = *(const float4*)&sX[4 * (tx + 16 * j) + xoff + 4 * kk4];
                float4 w4[8];
                #pragma unroll
                for (int i = 0; i < 8; ++i)
                    w4[i] = *(const float4*)&wbuf[(ty + 16 * i) * 68 + 4 * kk4];
                #pragma unroll
                for (int dk = 0; dk < 4; ++dk) {
                    #pragma unroll
                    for (int i = 0; i < 8; ++i) {
                        float wv = (&w4[i].x)[dk];
                        #pragma unroll
                        for (int j = 0; j < 8; ++j)
                            acc[i][j] = fmaf(wv, (&xq[j].x)[dk], acc[i][j]);
                    }
                }
            }

            if (kc < 3) {
                float4* dst = (float4*)sW[(kc + 1) & 1];
                #pragma unroll
                for (int w = 0; w < 8; ++w)
                    dst[sc * 17 + sg + w] = pre[w];
            }
            __syncthreads();
        }
    }

    // epilogue: locked fp32 elementwise chain; s-contiguous stores
    #pragma unroll
    for (int j = 0; j < 8; ++j) {
        int s = s0 + tx + 16 * j;
        if (s < SS) {
            #pragma unroll
            for (int i = 0; i < 8; ++i) {
                int c = ty + 16 * i;
                size_t idx = (size_t)(b * CC + c) * SS + s;
                if (MODE == 0) {
                    float d = acc[i][j];
                    drive[idx] = d;
                    u[idx] = __fmul_rn(STEP, d);   // u1 = 0 + 0.1f*drive
                } else {
                    float uo = u[idx];
                    float dr = drive[idx];
                    float a  = (fabsf(uo) > THRS) ? uo : 0.f;
                    float t1 = __fsub_rn(dr, uo);
                    float t2 = __fsub_rn(t1, acc[i][j]);
                    float t3 = __fadd_rn(t2, a);
                    float t4 = __fmul_rn(STEP, t3);
                    float un = __fadd_rn(uo, t4);
                    if (MODE == 1) u[idx] = un;
                    else           u[idx] = (fabsf(un) > THRS) ? un : 0.f;  // final
                }
            }
        }
    }
}

// ---------------------------------------------------------------------------
// float readlane via int builtin (lane is compile-time constant here)
// ---------------------------------------------------------------------------
__device__ __forceinline__ float rdlane_f(float v, int lane) {
    union { float f; int i; } u;
    u.f = v;
    u.i = __builtin_amdgcn_readlane(u.i, lane);
    return u.f;
}

// ---------------------------------------------------------------------------
// Transpose-conv (recon). Chain [bit-path frozen] identical to R5-R16:
//   recon[b][4m+r]: for c = 0..127 asc (4 stages x 32), q = 0..63 asc:
//       acc_r = fmaf(a[b][c][m-63+q], W[c][4*(63-q)+r], acc_r)
// R17 = R14 schedule (256 thr, m-tile 256, grid (16,16) — best measured)
// with deeper load pipelining: __launch_bounds__(256,1) unleashes VGPRs;
// per cl ALL 64 a-values are pulled into registers first (32 paired
// ds_read2 issues), then 64 q of pure VALU. Tests the hypothesis that the
// ~100us stall is shallow ds_read in-flight depth (VGPR_Count was 68).
// ---------------------------------------------------------------------------
__global__ __launch_bounds__(256, 1) void k_recon(
    const float* __restrict__ u,
    const float* __restrict__ W,       // [C][K] natural layout
    float* __restrict__ recon)         // [B][LL]
{
    __shared__ __align__(16) float sA[32 * 320];   // 40.96 KB (stride 320)
    __shared__ int sFlag;

    const int tid = threadIdx.x;      // = m_local in [0,256)
    const int lane = tid & 63;
    const int m0 = blockIdx.x * 256;
    const int b  = blockIdx.y;
    const int m  = m0 + tid;

    if (tid == 0) sFlag = 0;
    __syncthreads();

    float acc0 = 0.f, acc1 = 0.f, acc2 = 0.f, acc3 = 0.f;

    for (int cs = 0; cs < 4; ++cs) {            // 32-channel stages, c ascending
        const int c0 = cs * 32;
        bool nz = false;
        for (int cl = 0; cl < 32; ++cl) {
            const float* urow = u + (size_t)(b * CC + c0 + cl) * SS + (m0 - 63);
            #pragma unroll
            for (int h = 0; h < 2; ++h) {
                int col = tid + 256 * h;
                if (col < 319) {
                    int mm = m0 - 63 + col;
                    float v = 0.f;
                    if (mm >= 0 && mm < SS) {
                        float uu = urow[col];
                        v = (fabsf(uu) > THRS) ? uu : 0.f;
                    }
                    sA[cl * 320 + col] = v;
                    nz |= (v != 0.f);
                }
            }
        }
        if (nz) atomicOr(&sFlag, 1);
        __syncthreads();                        // staging + flags complete
        const int f = sFlag;                    // block-uniform read
        __syncthreads();                        // all threads have read f
        if (tid == 0) sFlag = 0;                // reset (ordered by loop-end barrier)

        if (f) {
            for (int cl = 0; cl < 32; ++cl) {   // c ascending
                const float* arow = sA + cl * 320 + tid;     // arow[q] = a[c][m-63+q]
                float4 wv = ((const float4*)(W + (size_t)(c0 + cl) * KK))[lane];

                // pull the whole 64-tap a-window into registers first
                // (32 ds_read2_b32 issues, all independent)
                float av[64];
                #pragma unroll
                for (int t = 0; t < 64; ++t) av[t] = arow[t];

                #pragma unroll
                for (int q = 0; q < 64; ++q) {  // j = 63-q descending
                    float wx = rdlane_f(wv.x, 63 - q);
                    float wy = rdlane_f(wv.y, 63 - q);
                    float wz = rdlane_f(wv.z, 63 - q);
                    float ww = rdlane_f(wv.w, 63 - q);
                    acc0 = fmaf(av[q], wx, acc0);
                    acc1 = fmaf(av[q], wy, acc1);
                    acc2 = fmaf(av[q], wz, acc2);
                    acc3 = fmaf(av[q], ww, acc3);
                }
            }
        }
        __syncthreads();   // sA reads done + sFlag reset visible before next stage
    }

    if (m < MM) {
        float4* o = (float4*)(recon + (size_t)b * LL + 4 * m);
        *o = make_float4(acc0, acc1, acc2, acc3);
    }
}

extern "C" void kernel_launch(void* const* d_in, const int* in_sizes, int n_in,
                              void* d_out, int out_size, void* d_ws, size_t ws_size,
                              hipStream_t stream) {
    const float* x = (const float*)d_in[0];   // [16][1][16000]
    const float* W = (const float*)d_in[1];   // [128][1][256]
    float* u = (float*)d_out;                 // u lives in d_out (fp32)

    float* ws    = (float*)d_ws;              // ~33.3 MB used
    float* drive = ws;                                    // 8062976
    float* recon = drive + (size_t)BB * CC * SS;          // 256000

    dim3 gConv(31, 16);   // ceil(3937/128) x B
    k_conv<0><<<gConv, 256, 0, stream>>>(x, W, drive, u);   // drive + u1

    for (int it = 0; it < 9; ++it) {   // iterations 2..10
        k_recon<<<dim3(16, 16), 256, 0, stream>>>(u, W, recon);
        if (it < 8)
            k_conv<1><<<gConv, 256, 0, stream>>>(recon, W, drive, u);
        else
            k_conv<2><<<gConv, 256, 0, stream>>>(recon, W, drive, u);  // final -> d_out
    }
}